// Round 12
// baseline (610.629 us; speedup 1.0000x reference)
//
#include <hip/hip_runtime.h>
#include <hip/hip_bf16.h>
#include <stdint.h>

// Problem constants (PolyhedronModel CGConv): fixed sizes per reference.
#define NN 50000      // nodes
#define EE 800000     // edges
#define CC 64        // node channels
#define DE 32        // edge feature dim
#define KD 160       // 2*CC + DE
#define NC 128       // combined output cols: [Wf | Ws]
#define GG 512       // graphs

typedef __attribute__((ext_vector_type(8))) short bf16x8;   // 8 bf16 (4 VGPR)
typedef __attribute__((ext_vector_type(4))) float f32x4;    // MFMA acc

__device__ __forceinline__ float sigmoidf_(float v) {
  return __fdividef(1.f, 1.f + __expf(-v));
}
// jax.nn.softplus(x) = max(x,0) + log1p(exp(-|x|))
__device__ __forceinline__ float softplusf_(float v) {
  return fmaxf(v, 0.f) + __logf(1.f + __expf(-fabsf(v)));
}
// Truncation split: f = hi + lo, lo captured exactly then truncated to bf16.
// Dropped lo*lo term => ~2^-16 relative product error.
__device__ __forceinline__ void tsplit(float f, short& hi, short& lo) {
  uint32_t u = __float_as_uint(f);
  float lf = f - __uint_as_float(u & 0xFFFF0000u);
  hi = (short)(u >> 16);
  lo = (short)(__float_as_uint(lf) >> 16);
}

// ---------------- CSR build (by dst) ----------------
__global__ void count_kernel(const int* __restrict__ ei, int* __restrict__ deg) {
  int e = blockIdx.x * 256 + threadIdx.x;          // grid exact: EE/256
  atomicAdd(&deg[ei[EE + e]], 1);                  // dst row
}

// Single-block fused scan: pos = exclusive-scan(deg), cursor = pos copy.
// 1024 threads, 49 sweeps of 1024; wave-shfl scan (no LDS ping-pong).
__global__ __launch_bounds__(1024) void scan_fused_kernel(
    const int* __restrict__ deg, int* __restrict__ pos, int* __restrict__ cursor) {
  __shared__ int ws[16];
  const int t = threadIdx.x;
  const int lane = t & 63, wv = t >> 6;
  int carry = 0;
  if (t == 0) { pos[0] = 0; cursor[0] = 0; }
  for (int base = 0; base < NN; base += 1024) {
    const int i = base + t;
    int v = (i < NN) ? deg[i] : 0;
    #pragma unroll
    for (int off = 1; off < 64; off <<= 1) {       // wave inclusive scan
      int u = __shfl_up(v, off, 64);
      if (lane >= off) v += u;
    }
    if (lane == 63) ws[wv] = v;
    __syncthreads();
    if (wv == 0 && lane < 16) {                    // scan the 16 wave sums
      int s = ws[lane];
      #pragma unroll
      for (int off = 1; off < 16; off <<= 1) {
        int u = __shfl_up(s, off, 64);
        if (lane >= off) s += u;
      }
      ws[lane] = s;
    }
    __syncthreads();
    const int add = (wv > 0 ? ws[wv - 1] : 0) + carry;
    if (i < NN) {
      const int incl = v + add;
      pos[i + 1] = incl;
      if (i < NN - 1) cursor[i + 1] = incl;
    }
    carry += ws[15];
    __syncthreads();                               // guard ws reuse next sweep
  }
}

// fill emits slot-ordered eidx/dst/src so downstream reads are coalesced.
__global__ void fill_kernel(const int* __restrict__ ei, int* __restrict__ cursor,
                            int* __restrict__ eidx, int* __restrict__ dsts,
                            int* __restrict__ srcs) {
  int e = blockIdx.x * 256 + threadIdx.x;
  int d = ei[EE + e];
  int s = ei[e];
  int slot = atomicAdd(&cursor[d], 1);
  eidx[slot] = e;
  dsts[slot] = d;
  srcs[slot] = s;
}

// ---------------- Prep: xsplit (+ wprep folded into tail blocks) ------------
// blocks [0,3125): x -> bf16 hi/lo.  blocks [3125,3205): pack W=[Wf|Ws] into
// B-fragment order (lane l supplies B[k=8*(l>>4)+i][n=l&15], i=0..7;
// pack p = ((s*8+nt)*64+l)*8+i).
__global__ void xsplit_wprep_kernel(const float* __restrict__ x,
                                    unsigned short* __restrict__ xhi,
                                    unsigned short* __restrict__ xlo,
                                    const float* __restrict__ Wf,
                                    const float* __restrict__ Ws,
                                    short* __restrict__ Bph,
                                    short* __restrict__ Bpl) {
  if (blockIdx.x < 3125) {
    int idx = blockIdx.x * 256 + threadIdx.x;      // NN*CC/4 = 800000 float4
    float4 v = ((const float4*)x)[idx];
    ushort4 h, l;
    short a, b;
    tsplit(v.x, a, b); h.x = (unsigned short)a; l.x = (unsigned short)b;
    tsplit(v.y, a, b); h.y = (unsigned short)a; l.y = (unsigned short)b;
    tsplit(v.z, a, b); h.z = (unsigned short)a; l.z = (unsigned short)b;
    tsplit(v.w, a, b); h.w = (unsigned short)a; l.w = (unsigned short)b;
    *(ushort4*)(xhi + (size_t)idx * 4) = h;
    *(ushort4*)(xlo + (size_t)idx * 4) = l;
  } else {
    int p = (blockIdx.x - 3125) * 256 + threadIdx.x;   // 20480 total
    int i = p & 7, l = (p >> 3) & 63, tile = p >> 9;
    int nt = tile & 7, s = tile >> 3;
    int k = s * 32 + 8 * (l >> 4) + i;
    int col = nt * 16 + (l & 15);
    float w = (col < CC) ? Wf[k * CC + col] : Ws[k * CC + (col - CC)];
    short hi, lo;
    tsplit(w, hi, lo);
    Bph[p] = hi;
    Bpl[p] = lo;
  }
}

// ---------------- Prep: gather ea into SLOT order, pre-split hi/lo ----------
// eap row (128B) layout: 4 chunks of [8 hi shorts | 8 lo shorts].
// Converts edge kstep-4 from 64-random-row gather (L3/HBM latency) to a
// contiguous 2KB stream per mt-tile.
__global__ void eaprep_kernel(const float* __restrict__ ea,
                              const int* __restrict__ eidx,
                              unsigned short* __restrict__ eap) {
  int tid = blockIdx.x * 256 + threadIdx.x;        // grid exact: EE*4/256
  int slot = tid >> 2, c = tid & 3;
  int e = eidx[slot];
  const float4* s4 = (const float4*)(ea + (size_t)e * DE + c * 8);
  float4 a = s4[0], b = s4[1];
  float v[8] = {a.x, a.y, a.z, a.w, b.x, b.y, b.z, b.w};
  bf16x8 h, l;
  #pragma unroll
  for (int i = 0; i < 8; ++i) {
    short hh, ll;
    tsplit(v[i], hh, ll);
    h[i] = hh;
    l[i] = ll;
  }
  unsigned short* o = eap + (size_t)slot * 64 + c * 16;
  *(bf16x8*)o = h;
  *(bf16x8*)(o + 8) = l;
}

// ---------------- Edge kernel (MFMA bf16x3), dst-sorted slot order ----------
// 512 thr = 8 waves; 256 slots/block. Wave (mg,ng): 64 edges x 64 cols.
// Bh (40KB) in LDS, Bl from global (L1-hot). EAP: kstep4 streams slot-ordered
// pre-split ea; else r8 fallback (eidx gather + tsplit).
template <bool EAP>
__global__ __launch_bounds__(512) void edge_mfma_kernel(
    const unsigned short* __restrict__ xhi, const unsigned short* __restrict__ xlo,
    const unsigned short* __restrict__ eap,
    const int* __restrict__ eidx, const int* __restrict__ dsts,
    const int* __restrict__ srcs, const float* __restrict__ ea,
    const short* __restrict__ Bph, const short* __restrict__ Bpl,
    const float* __restrict__ bfv, const float* __restrict__ bsv,
    float* __restrict__ msg)
{
  __shared__ short Bh[20480];   // 40 KiB
  const int t = threadIdx.x;

  {  // stage packed hi weights: 5 x 512 float4
    const float4* gh = (const float4*)Bph;
    float4* sh = (float4*)Bh;
    #pragma unroll
    for (int r = 0; r < 5; ++r) sh[r * 512 + t] = gh[r * 512 + t];
  }

  const int w  = t >> 6, l = t & 63;
  const int mg = w >> 1, ng = w & 1;
  const int sbase = blockIdx.x * 256 + mg * 64;    // slot base for this wave
  const int lr = l & 15, lg = l >> 4;

  int dst[4], src[4], ep[4];
  #pragma unroll
  for (int mt = 0; mt < 4; ++mt) {
    const int slot = sbase + mt * 16 + lr;
    dst[mt] = dsts[slot];                          // sorted => L1-broadcast
    src[mt] = srcs[slot];
    if constexpr (!EAP) ep[mt] = eidx[slot];
  }
  __syncthreads();

  f32x4 acc[4][4];   // [m-tile][q]; q 0,1 = F cols, 2,3 = S cols
  #pragma unroll
  for (int mt = 0; mt < 4; ++mt)
    #pragma unroll
    for (int q = 0; q < 4; ++q) acc[mt][q] = (f32x4){0.f, 0.f, 0.f, 0.f};

  const bf16x8* Blg = (const bf16x8*)Bpl;

  #pragma unroll
  for (int s = 0; s < 5; ++s) {
    // ---- A fragments (hi/lo) ----
    bf16x8 ah[4], al[4];
    if (s < 4) {
      const int koff = (s & 1) * 32 + 8 * lg;
      #pragma unroll
      for (int mt = 0; mt < 4; ++mt) {
        const int row = (s < 2) ? dst[mt] : src[mt];
        const size_t o = (size_t)row * CC + koff;
        ah[mt] = *(const bf16x8*)(xhi + o);
        al[mt] = *(const bf16x8*)(xlo + o);
      }
    } else if constexpr (EAP) {
      #pragma unroll
      for (int mt = 0; mt < 4; ++mt) {             // contiguous 2KB per mt
        const unsigned short* o = eap + (size_t)(sbase + mt * 16 + lr) * 64 + lg * 16;
        ah[mt] = *(const bf16x8*)o;
        al[mt] = *(const bf16x8*)(o + 8);
      }
    } else {
      #pragma unroll
      for (int mt = 0; mt < 4; ++mt) {
        const float4* p4 = (const float4*)(ea + (size_t)ep[mt] * DE + 8 * lg);
        float4 v0 = p4[0], v1 = p4[1];
        float v[8] = {v0.x, v0.y, v0.z, v0.w, v1.x, v1.y, v1.z, v1.w};
        #pragma unroll
        for (int i = 0; i < 8; ++i) {
          short hh, ll;
          tsplit(v[i], hh, ll);
          ah[mt][i] = hh;
          al[mt][i] = ll;
        }
      }
    }
    // ---- B fragments: hi from LDS, lo from global ----
    bf16x8 bh[4], bl[4];
    #pragma unroll
    for (int q = 0; q < 4; ++q) {
      const int nt = 2 * ng + (q & 1) + (q >> 1) * 4;
      bh[q] = *(const bf16x8*)(Bh + ((s * 8 + nt) * 64 + l) * 8);
      bl[q] = Blg[(s * 8 + nt) * 64 + l];
    }
    // ---- 3-product compensated MFMA ----
    #pragma unroll
    for (int mt = 0; mt < 4; ++mt)
      #pragma unroll
      for (int q = 0; q < 4; ++q)
        acc[mt][q] = __builtin_amdgcn_mfma_f32_16x16x32_bf16(ah[mt], bh[q], acc[mt][q], 0, 0, 0);
    #pragma unroll
    for (int mt = 0; mt < 4; ++mt)
      #pragma unroll
      for (int q = 0; q < 4; ++q)
        acc[mt][q] = __builtin_amdgcn_mfma_f32_16x16x32_bf16(al[mt], bh[q], acc[mt][q], 0, 0, 0);
    #pragma unroll
    for (int mt = 0; mt < 4; ++mt)
      #pragma unroll
      for (int q = 0; q < 4; ++q)
        acc[mt][q] = __builtin_amdgcn_mfma_f32_16x16x32_bf16(ah[mt], bl[q], acc[mt][q], 0, 0, 0);
  }

  // ---- epilogue: bias + sigmoid*softplus, store msg at SLOT rows ----
  // C/D layout (verified): col = lane&15, row = (lane>>4)*4 + reg.
  #pragma unroll
  for (int p2 = 0; p2 < 2; ++p2) {
    const int ch = (2 * ng + p2) * 16 + lr;
    const float bF = bfv[ch], bS = bsv[ch];
    #pragma unroll
    for (int mt = 0; mt < 4; ++mt) {
      f32x4 F = acc[mt][p2];
      f32x4 S = acc[mt][p2 + 2];
      #pragma unroll
      for (int r = 0; r < 4; ++r) {
        const int oslot = sbase + mt * 16 + lg * 4 + r;
        msg[(size_t)oslot * CC + ch] = sigmoidf_(F[r] + bF) * softplusf_(S[r] + bS);
      }
    }
  }
}

// ---------------- Fused gather + node head: contiguous segmented reduce -----
// 8 threads/node (thread i owns channels 8i..8i+7); 1-deep load pipeline.
__global__ __launch_bounds__(256) void gather_node_kernel(
    const float* __restrict__ msg, const int* __restrict__ pos,
    const float* __restrict__ x, const int* __restrict__ batch,
    const float* __restrict__ W1, const float* __restrict__ b1,
    float* __restrict__ pool)
{
  const int t = threadIdx.x;
  const int n = blockIdx.x * 32 + (t >> 3);
  if (n >= NN) return;
  const int i = t & 7;
  const int start = pos[n], end = pos[n + 1];

  float4 a0 = make_float4(0.f, 0.f, 0.f, 0.f);
  float4 a1 = make_float4(0.f, 0.f, 0.f, 0.f);
  const float4* m4 = (const float4*)msg;
  float4 c0, c1;
  if (start < end) {
    c0 = m4[(size_t)start * 16 + 2 * i];
    c1 = m4[(size_t)start * 16 + 2 * i + 1];
  }
  for (int p = start; p < end; ++p) {
    float4 u0 = c0, u1 = c1;
    if (p + 1 < end) {                              // prefetch next row
      c0 = m4[(size_t)(p + 1) * 16 + 2 * i];
      c1 = m4[(size_t)(p + 1) * 16 + 2 * i + 1];
    }
    a0.x += u0.x; a0.y += u0.y; a0.z += u0.z; a0.w += u0.w;
    a1.x += u1.x; a1.y += u1.y; a1.z += u1.z; a1.w += u1.w;
  }

  const float4 x0 = *(const float4*)(x + (size_t)n * CC + 8 * i);
  const float4 x1 = *(const float4*)(x + (size_t)n * CC + 8 * i + 4);
  float h[8];
  h[0] = sigmoidf_(x0.x + a0.x); h[1] = sigmoidf_(x0.y + a0.y);
  h[2] = sigmoidf_(x0.z + a0.z); h[3] = sigmoidf_(x0.w + a0.w);
  h[4] = sigmoidf_(x1.x + a1.x); h[5] = sigmoidf_(x1.y + a1.y);
  h[6] = sigmoidf_(x1.z + a1.z); h[7] = sigmoidf_(x1.w + a1.w);

  float o[6];
  #pragma unroll
  for (int j = 0; j < 6; ++j) o[j] = 0.f;
  #pragma unroll
  for (int c = 0; c < 8; ++c) {
    const float* wp = W1 + (size_t)(8 * i + c) * 6;
    #pragma unroll
    for (int j = 0; j < 6; ++j) o[j] = fmaf(h[c], wp[j], o[j]);
  }
  #pragma unroll
  for (int d = 4; d > 0; d >>= 1) {
    #pragma unroll
    for (int j = 0; j < 6; ++j) o[j] += __shfl_down(o[j], d, 8);
  }
  if (i == 0) {
    int g = batch[n];
    #pragma unroll
    for (int j = 0; j < 6; ++j)
      atomicAdd(&pool[g * 6 + j], sigmoidf_(o[j] + b1[j]));
  }
}

// Head: out[g] = relu(pool[g] @ W2 + b2)
__global__ void out_kernel(const float* __restrict__ pool,
                           const float* __restrict__ W2,
                           const float* __restrict__ b2,
                           float* __restrict__ out)
{
  int g = blockIdx.x * 64 + threadIdx.x;
  if (g < GG) {
    float acc = b2[0];
    #pragma unroll
    for (int j = 0; j < 6; ++j) acc = fmaf(pool[g * 6 + j], W2[j], acc);
    out[g] = fmaxf(acc, 0.f);
  }
}

static inline size_t al64(size_t v) { return (v + 63) & ~(size_t)63; }

extern "C" void kernel_launch(void* const* d_in, const int* in_sizes, int n_in,
                              void* d_out, int out_size, void* d_ws, size_t ws_size,
                              hipStream_t stream) {
  const float* x     = (const float*)d_in[0];
  const int*   ei    = (const int*)d_in[1];
  const float* ea    = (const float*)d_in[2];
  const int*   batch = (const int*)d_in[3];
  // d_in[4] = num_graphs scalar — fixed sizes
  const float* Wf = (const float*)d_in[5];
  const float* bf = (const float*)d_in[6];
  const float* Ws = (const float*)d_in[7];
  const float* bs = (const float*)d_in[8];
  const float* W1 = (const float*)d_in[9];
  const float* b1 = (const float*)d_in[10];
  const float* W2 = (const float*)d_in[11];
  const float* b2 = (const float*)d_in[12];
  float* out = (float*)d_out;

  // Workspace: msg | xhi | xlo | Bph | Bpl | deg | pos | cursor
  //            | eidx | dsts | srcs | pool | [eap]
  char* p = (char*)d_ws;
  float* msg = (float*)p;            p += al64((size_t)EE * CC * 4);
  unsigned short* xhi = (unsigned short*)p; p += al64((size_t)NN * CC * 2);
  unsigned short* xlo = (unsigned short*)p; p += al64((size_t)NN * CC * 2);
  short* Bph = (short*)p;            p += al64((size_t)KD * NC * 2);
  short* Bpl = (short*)p;            p += al64((size_t)KD * NC * 2);
  int* deg    = (int*)p;             p += al64((size_t)NN * 4);
  int* pos    = (int*)p;             p += al64((size_t)(NN + 1) * 4);
  int* cursor = (int*)p;             p += al64((size_t)NN * 4);
  int* eidx   = (int*)p;             p += al64((size_t)EE * 4);
  int* dsts   = (int*)p;             p += al64((size_t)EE * 4);
  int* srcs   = (int*)p;             p += al64((size_t)EE * 4);
  float* pool = (float*)p;           p += al64((size_t)GG * 6 * 4);
  unsigned short* eap = (unsigned short*)p;
  const bool use_eap =
      ((size_t)(p - (char*)d_ws) + al64((size_t)EE * 64 * 2)) <= ws_size;

  hipMemsetAsync(deg, 0, (size_t)NN * 4, stream);
  hipMemsetAsync(pool, 0, (size_t)GG * 6 * 4, stream);

  xsplit_wprep_kernel<<<3205, 256, 0, stream>>>(x, xhi, xlo, Wf, Ws, Bph, Bpl);
  count_kernel<<<EE / 256, 256, 0, stream>>>(ei, deg);
  scan_fused_kernel<<<1, 1024, 0, stream>>>(deg, pos, cursor);
  fill_kernel<<<EE / 256, 256, 0, stream>>>(ei, cursor, eidx, dsts, srcs);

  if (use_eap) {
    eaprep_kernel<<<EE * 4 / 256, 256, 0, stream>>>(ea, eidx, eap);
    edge_mfma_kernel<true><<<EE / 256, 512, 0, stream>>>(
        xhi, xlo, eap, eidx, dsts, srcs, ea, Bph, Bpl, bf, bs, msg);
  } else {
    edge_mfma_kernel<false><<<EE / 256, 512, 0, stream>>>(
        xhi, xlo, eap, eidx, dsts, srcs, ea, Bph, Bpl, bf, bs, msg);
  }
  gather_node_kernel<<<(NN + 31) / 32, 256, 0, stream>>>(msg, pos, x, batch, W1, b1, pool);
  out_kernel<<<(GG + 63) / 64, 64, 0, stream>>>(pool, W2, b2, out);
}